// Round 1
// baseline (10002.058 us; speedup 1.0000x reference)
//
#include <hip/hip_runtime.h>
#include <stdint.h>

#define SEQ   2048
#define BATCH 128
#define DIN   256
#define DH    512
#define DOUT  256

typedef uint16_t u16;
typedef uint32_t u32;
typedef __attribute__((ext_vector_type(8))) short short8;
typedef __attribute__((ext_vector_type(4))) float f32x4;

__device__ __forceinline__ u16 f2bf(float f) {
    u32 u = __float_as_uint(f);
    u += 0x7fffu + ((u >> 16) & 1u);   // RNE
    return (u16)(u >> 16);
}
__device__ __forceinline__ float bf2f(u16 h) {
    return __uint_as_float(((u32)h) << 16);
}
__device__ __forceinline__ float tanh_fast(float x) {
    float e = __expf(2.0f * x);                       // inf for large x -> rcp=0 -> 1
    return 1.0f - 2.0f * __builtin_amdgcn_rcpf(e + 1.0f);
}

// ---------------------------------------------------------------------------
// Pack W_hh (fp32 [512][512], row=n, col=k) into MFMA-fragment order (bf16):
// Wp[((wv*2+nt)*16+kc)*512 + lane*8 + j] = W_hh[wv*32+nt*16+(lane&15)][kc*32+(lane>>4)*8+j]
// so each wave's B-fragment load is one coalesced dwordx4 (1 KB/wave).
// ---------------------------------------------------------------------------
__global__ void pack_whh_kernel(const float* __restrict__ W, u16* __restrict__ Wp) {
    int idx  = blockIdx.x * 256 + threadIdx.x;    // 0..32767
    int lane = idx & 63;
    int kc   = (idx >> 6) & 15;
    int nt   = (idx >> 10) & 1;
    int wv   = idx >> 11;                          // 0..15
    int n  = wv * 32 + nt * 16 + (lane & 15);
    int k0 = kc * 32 + (lane >> 4) * 8;
    short8 v;
#pragma unroll
    for (int j = 0; j < 8; ++j) v[j] = (short)f2bf(W[(size_t)n * DH + k0 + j]);
    *reinterpret_cast<short8*>(Wp + (size_t)idx * 8) = v;
}

// ---------------------------------------------------------------------------
// Phase 1: xp[s*B+b][h] = bf16( x[s,b,:]·W_ih[h,:] + b_ih[h] + b_hh[h] )
// M=262144, N=512, K=256.  Tile: 128(M) x 256(N), BK=64, 8 waves.
// ---------------------------------------------------------------------------
__global__ __launch_bounds__(512) void xproj_kernel(
    const float* __restrict__ x, const float* __restrict__ W_ih,
    const float* __restrict__ b_ih, const float* __restrict__ b_hh,
    u16* __restrict__ xp) {
    __shared__ u16 As[128 * 64];
    __shared__ u16 Bs[256 * 64];
    const int tid  = threadIdx.x;
    const int lane = tid & 63;
    const int wid  = tid >> 6;     // 0..7
    const int wm   = wid >> 2;     // 0..1
    const int wn   = wid & 3;      // 0..3
    const int mt   = blockIdx.x;   // 0..2047
    const int nt   = blockIdx.y;   // 0..1

    f32x4 acc[4][4];
#pragma unroll
    for (int i = 0; i < 4; ++i)
#pragma unroll
        for (int j = 0; j < 4; ++j) acc[i][j] = (f32x4){0.f, 0.f, 0.f, 0.f};

    for (int kk = 0; kk < DIN; kk += 64) {
        __syncthreads();
        {   // stage A: 128 rows x 64 k (fp32 -> bf16), 16 elems/thread
            int r = tid >> 2, q = tid & 3;
            const float4* gp = (const float4*)(x + (size_t)(mt * 128 + r) * DIN + kk + q * 16);
            float4 v0 = gp[0], v1 = gp[1], v2 = gp[2], v3 = gp[3];
            short8 h0, h1;
            h0[0]=(short)f2bf(v0.x); h0[1]=(short)f2bf(v0.y); h0[2]=(short)f2bf(v0.z); h0[3]=(short)f2bf(v0.w);
            h0[4]=(short)f2bf(v1.x); h0[5]=(short)f2bf(v1.y); h0[6]=(short)f2bf(v1.z); h0[7]=(short)f2bf(v1.w);
            h1[0]=(short)f2bf(v2.x); h1[1]=(short)f2bf(v2.y); h1[2]=(short)f2bf(v2.z); h1[3]=(short)f2bf(v2.w);
            h1[4]=(short)f2bf(v3.x); h1[5]=(short)f2bf(v3.y); h1[6]=(short)f2bf(v3.z); h1[7]=(short)f2bf(v3.w);
            int base = r * 64, sw = (r & 7) << 3, ke = q * 16;
            *(short8*)&As[base + (ke ^ sw)]       = h0;
            *(short8*)&As[base + ((ke + 8) ^ sw)] = h1;
        }
        {   // stage B: 256 rows x 64 k, 32 elems/thread
            int r = tid >> 1, hf = tid & 1;
            const float4* gp = (const float4*)(W_ih + (size_t)(nt * 256 + r) * DIN + kk + hf * 32);
            int base = r * 64, sw = (r & 7) << 3;
#pragma unroll
            for (int cp = 0; cp < 2; ++cp) {
                float4 u0 = gp[cp*4+0], u1 = gp[cp*4+1], u2 = gp[cp*4+2], u3 = gp[cp*4+3];
                short8 t0, t1;
                t0[0]=(short)f2bf(u0.x); t0[1]=(short)f2bf(u0.y); t0[2]=(short)f2bf(u0.z); t0[3]=(short)f2bf(u0.w);
                t0[4]=(short)f2bf(u1.x); t0[5]=(short)f2bf(u1.y); t0[6]=(short)f2bf(u1.z); t0[7]=(short)f2bf(u1.w);
                t1[0]=(short)f2bf(u2.x); t1[1]=(short)f2bf(u2.y); t1[2]=(short)f2bf(u2.z); t1[3]=(short)f2bf(u2.w);
                t1[4]=(short)f2bf(u3.x); t1[5]=(short)f2bf(u3.y); t1[6]=(short)f2bf(u3.z); t1[7]=(short)f2bf(u3.w);
                int ke = hf * 32 + cp * 16;
                *(short8*)&Bs[base + (ke ^ sw)]       = t0;
                *(short8*)&Bs[base + ((ke + 8) ^ sw)] = t1;
            }
        }
        __syncthreads();
#pragma unroll
        for (int kt = 0; kt < 2; ++kt) {
            short8 a[4], b[4];
            int ke = kt * 32 + (lane >> 4) * 8;
#pragma unroll
            for (int mi = 0; mi < 4; ++mi) {
                int rr = wm * 64 + mi * 16 + (lane & 15);
                a[mi] = *(const short8*)&As[rr * 64 + (ke ^ ((rr & 7) << 3))];
            }
#pragma unroll
            for (int ni = 0; ni < 4; ++ni) {
                int rr = wn * 64 + ni * 16 + (lane & 15);
                b[ni] = *(const short8*)&Bs[rr * 64 + (ke ^ ((rr & 7) << 3))];
            }
#pragma unroll
            for (int mi = 0; mi < 4; ++mi)
#pragma unroll
                for (int ni = 0; ni < 4; ++ni)
                    acc[mi][ni] = __builtin_amdgcn_mfma_f32_16x16x32_bf16(a[mi], b[ni], acc[mi][ni], 0, 0, 0);
        }
    }
    // epilogue: C[m][n]: row = 4*(lane>>4)+r, col = lane&15
    int g4 = lane >> 4, c = lane & 15;
#pragma unroll
    for (int ni = 0; ni < 4; ++ni) {
        int col = nt * 256 + wn * 64 + ni * 16 + c;
        float bias = b_ih[col] + b_hh[col];
#pragma unroll
        for (int mi = 0; mi < 4; ++mi) {
#pragma unroll
            for (int r = 0; r < 4; ++r) {
                int row = mt * 128 + wm * 64 + mi * 16 + 4 * g4 + r;
                xp[(size_t)row * DH + col] = f2bf(acc[mi][ni][r] + bias);
            }
        }
    }
}

// ---------------------------------------------------------------------------
// Phase 2: recurrence. 8 blocks x 1024 thr (16 waves). Block owns 16 batch
// rows; wave wv owns H-cols [32wv, 32wv+32). h double-buffered in LDS
// (XOR-swizzled), W_hh streamed from L2 in packed fragment order, xp
// prefetched to regs and written to LDS post-compute. 1 barrier/step.
// ---------------------------------------------------------------------------
__global__ __launch_bounds__(1024) void rnn_rec_kernel(
    const u16* __restrict__ xp, const u16* __restrict__ Wp,
    u16* __restrict__ h_last) {
    __shared__ u16 h_s[2][16 * 512];
    __shared__ u16 xp_s[2][16 * 512];
    const int tid = threadIdx.x, lane = tid & 63, wv = tid >> 6;
    const int b0 = blockIdx.x * 16;

    {   // h0 = 0 ; stage xp[t=0]
        *(short8*)&h_s[0][tid * 8] = (short8)0;
        short8 v = *(const short8*)(xp + ((size_t)0 * BATCH + b0) * DH + tid * 8);
        *(short8*)&xp_s[0][tid * 8] = v;
    }
    __syncthreads();

    const int g4 = lane >> 4, c = lane & 15;
    const int arow = lane & 15;
    const int asw = (arow & 7) << 3;
    const u16* wp0 = Wp + (size_t)(wv * 2 + 0) * 16 * 512 + lane * 8;
    const u16* wp1 = Wp + (size_t)(wv * 2 + 1) * 16 * 512 + lane * 8;

    for (int t = 0; t < SEQ; ++t) {
        const int cur = t & 1, nxt = cur ^ 1;
        short8 xpv = (short8)0;
        const bool pf = (t + 1 < SEQ);
        if (pf) xpv = *(const short8*)(xp + ((size_t)(t + 1) * BATCH + b0) * DH + tid * 8);

        f32x4 acc0 = {0.f, 0.f, 0.f, 0.f}, acc1 = {0.f, 0.f, 0.f, 0.f};
#pragma unroll 4
        for (int kc = 0; kc < 16; ++kc) {
            int ke = kc * 32 + g4 * 8;
            short8 a  = *(const short8*)&h_s[cur][arow * 512 + (ke ^ asw)];
            short8 w0 = *(const short8*)(wp0 + kc * 512);
            short8 w1 = *(const short8*)(wp1 + kc * 512);
            acc0 = __builtin_amdgcn_mfma_f32_16x16x32_bf16(a, w0, acc0, 0, 0, 0);
            acc1 = __builtin_amdgcn_mfma_f32_16x16x32_bf16(a, w1, acc1, 0, 0, 0);
        }
        // epilogue: row = 4*g4+r (batch row), cols wv*32+c and +16
#pragma unroll
        for (int r = 0; r < 4; ++r) {
            int row = 4 * g4 + r;
            int col0 = wv * 32 + c, col1 = col0 + 16;
            float p0 = acc0[r] + bf2f(xp_s[cur][row * 512 + col0]);
            float p1 = acc1[r] + bf2f(xp_s[cur][row * 512 + col1]);
            int sw = (row & 7) << 3;
            h_s[nxt][row * 512 + (col0 ^ sw)] = f2bf(tanh_fast(p0));
            h_s[nxt][row * 512 + (col1 ^ sw)] = f2bf(tanh_fast(p1));
        }
        if (pf) *(short8*)&xp_s[nxt][tid * 8] = xpv;
        __syncthreads();
    }
    {   // final h lives in h_s[0] (SEQ even). Un-swizzle and store.
        int i = tid * 8;
        int row = i >> 9, col = i & 511;
        int sw = (row & 7) << 3;
        short8 v = *(const short8*)&h_s[0][row * 512 + (col ^ sw)];
        *(short8*)(h_last + (size_t)(b0 + row) * DH + col) = v;
    }
}

// ---------------------------------------------------------------------------
// Phase 3: out[b][o] = h_last[b,:]·W_fc[o,:] + b_fc[o]   (fp32 VALU, tiny)
// ---------------------------------------------------------------------------
__global__ __launch_bounds__(256) void fc_kernel(
    const u16* __restrict__ h_last, const float* __restrict__ W_fc,
    const float* __restrict__ b_fc, float* __restrict__ out) {
    __shared__ float hsh[DH];
    int b = blockIdx.x, o = threadIdx.x;
    for (int i = threadIdx.x; i < DH; i += 256) hsh[i] = bf2f(h_last[(size_t)b * DH + i]);
    __syncthreads();
    const float* w = W_fc + (size_t)o * DH;
    float s = 0.f;
#pragma unroll 8
    for (int k = 0; k < DH; ++k) s += hsh[k] * w[k];
    out[(size_t)b * DOUT + o] = s + b_fc[o];
}

extern "C" void kernel_launch(void* const* d_in, const int* in_sizes, int n_in,
                              void* d_out, int out_size, void* d_ws, size_t ws_size,
                              hipStream_t stream) {
    const float* x    = (const float*)d_in[0];
    const float* W_ih = (const float*)d_in[1];
    const float* W_hh = (const float*)d_in[2];
    const float* b_ih = (const float*)d_in[3];
    const float* b_hh = (const float*)d_in[4];
    const float* W_fc = (const float*)d_in[5];
    const float* b_fc = (const float*)d_in[6];
    float* out = (float*)d_out;

    u16* xp     = (u16*)d_ws;                               // 2048*128*512 bf16 = 256 MB
    u16* Wp     = xp + (size_t)SEQ * BATCH * DH;            // 512 KB
    u16* h_last = Wp + (size_t)16 * 2 * 16 * 512;           // 128 KB

    hipLaunchKernelGGL(pack_whh_kernel, dim3(128), dim3(256), 0, stream, W_hh, Wp);
    hipLaunchKernelGGL(xproj_kernel, dim3(2048, 2), dim3(512), 0, stream, x, W_ih, b_ih, b_hh, xp);
    hipLaunchKernelGGL(rnn_rec_kernel, dim3(8), dim3(1024), 0, stream, xp, Wp, h_last);
    hipLaunchKernelGGL(fc_kernel, dim3(128), dim3(256), 0, stream, h_last, W_fc, b_fc, out);
}

// Round 2
// 6758.056 us; speedup vs baseline: 1.4800x; 1.4800x over previous
//
#include <hip/hip_runtime.h>
#include <stdint.h>

#define SEQ   2048
#define BATCH 128
#define DIN   256
#define DH    512
#define DOUT  256

typedef uint16_t u16;
typedef uint32_t u32;
typedef __attribute__((ext_vector_type(8))) short short8;
typedef __attribute__((ext_vector_type(4))) float f32x4;

__device__ __forceinline__ u16 f2bf(float f) {
    u32 u = __float_as_uint(f);
    u += 0x7fffu + ((u >> 16) & 1u);   // RNE
    return (u16)(u >> 16);
}
__device__ __forceinline__ float bf2f(u16 h) {
    return __uint_as_float(((u32)h) << 16);
}
__device__ __forceinline__ float tanh_fast(float x) {
    float e = __expf(2.0f * x);                       // inf for large x -> rcp=0 -> 1
    return 1.0f - 2.0f * __builtin_amdgcn_rcpf(e + 1.0f);
}

// xp layout: XPIDX(t, bblk, wv, n, g4, c) + r  (u16 units)
// value = xp[t][batch = bblk*16 + g4*4 + r][hcol = wv*64 + n*16 + c]
__device__ __forceinline__ size_t xpidx(int t, int bb, int wv, int n, int g4, int c) {
    return ((((((size_t)t * 8 + bb) * 8 + wv) * 4 + n) * 4 + g4) * 16 + c) * 4;
}

// ---------------------------------------------------------------------------
// Pack W_hh (fp32 [512 n][512 k]) into per-wave MFMA fragment order (bf16):
// Wp[((wv*16+kc)*4+n)*512 + lane*8 + j] =
//     W[wv*64 + n*16 + (lane&15)][kc*32 + (lane>>4)*8 + j]
// ---------------------------------------------------------------------------
__global__ void pack_whh_kernel(const float* __restrict__ W, u16* __restrict__ Wp) {
    int idx  = blockIdx.x * 256 + threadIdx.x;    // 0..32767
    int lane = idx & 63;
    int n    = (idx >> 6) & 3;
    int kc   = (idx >> 8) & 15;
    int wv   = idx >> 12;                          // 0..7
    int col = wv * 64 + n * 16 + (lane & 15);
    int k0  = kc * 32 + (lane >> 4) * 8;
    short8 v;
#pragma unroll
    for (int j = 0; j < 8; ++j) v[j] = (short)f2bf(W[(size_t)col * DH + k0 + j]);
    *reinterpret_cast<short8*>(Wp + (size_t)idx * 8) = v;
}

// ---------------------------------------------------------------------------
// Phase 1: xp = x @ W_ih^T + b_ih + b_hh, bf16, written in xpidx layout.
// M=262144, N=512, K=256.  Tile: 128(M) x 256(N), BK=64, 8 waves.
// ---------------------------------------------------------------------------
__global__ __launch_bounds__(512) void xproj_kernel(
    const float* __restrict__ x, const float* __restrict__ W_ih,
    const float* __restrict__ b_ih, const float* __restrict__ b_hh,
    u16* __restrict__ xp) {
    __shared__ u16 As[128 * 64];
    __shared__ u16 Bs[256 * 64];
    const int tid  = threadIdx.x;
    const int lane = tid & 63;
    const int wid  = tid >> 6;     // 0..7
    const int wm   = wid >> 2;     // 0..1
    const int wn   = wid & 3;      // 0..3
    const int mt   = blockIdx.x;   // 0..2047
    const int nt   = blockIdx.y;   // 0..1

    f32x4 acc[4][4];
#pragma unroll
    for (int i = 0; i < 4; ++i)
#pragma unroll
        for (int j = 0; j < 4; ++j) acc[i][j] = (f32x4){0.f, 0.f, 0.f, 0.f};

    for (int kk = 0; kk < DIN; kk += 64) {
        __syncthreads();
        {   // stage A: 128 rows x 64 k (fp32 -> bf16), 16 elems/thread
            int r = tid >> 2, q = tid & 3;
            const float4* gp = (const float4*)(x + (size_t)(mt * 128 + r) * DIN + kk + q * 16);
            float4 v0 = gp[0], v1 = gp[1], v2 = gp[2], v3 = gp[3];
            short8 h0, h1;
            h0[0]=(short)f2bf(v0.x); h0[1]=(short)f2bf(v0.y); h0[2]=(short)f2bf(v0.z); h0[3]=(short)f2bf(v0.w);
            h0[4]=(short)f2bf(v1.x); h0[5]=(short)f2bf(v1.y); h0[6]=(short)f2bf(v1.z); h0[7]=(short)f2bf(v1.w);
            h1[0]=(short)f2bf(v2.x); h1[1]=(short)f2bf(v2.y); h1[2]=(short)f2bf(v2.z); h1[3]=(short)f2bf(v2.w);
            h1[4]=(short)f2bf(v3.x); h1[5]=(short)f2bf(v3.y); h1[6]=(short)f2bf(v3.z); h1[7]=(short)f2bf(v3.w);
            int base = r * 64, sw = (r & 7) << 3, ke = q * 16;
            *(short8*)&As[base + (ke ^ sw)]       = h0;
            *(short8*)&As[base + ((ke + 8) ^ sw)] = h1;
        }
        {   // stage B: 256 rows x 64 k, 32 elems/thread
            int r = tid >> 1, hf = tid & 1;
            const float4* gp = (const float4*)(W_ih + (size_t)(nt * 256 + r) * DIN + kk + hf * 32);
            int base = r * 64, sw = (r & 7) << 3;
#pragma unroll
            for (int cp = 0; cp < 2; ++cp) {
                float4 u0 = gp[cp*4+0], u1 = gp[cp*4+1], u2 = gp[cp*4+2], u3 = gp[cp*4+3];
                short8 t0, t1;
                t0[0]=(short)f2bf(u0.x); t0[1]=(short)f2bf(u0.y); t0[2]=(short)f2bf(u0.z); t0[3]=(short)f2bf(u0.w);
                t0[4]=(short)f2bf(u1.x); t0[5]=(short)f2bf(u1.y); t0[6]=(short)f2bf(u1.z); t0[7]=(short)f2bf(u1.w);
                t1[0]=(short)f2bf(u2.x); t1[1]=(short)f2bf(u2.y); t1[2]=(short)f2bf(u2.z); t1[3]=(short)f2bf(u2.w);
                t1[4]=(short)f2bf(u3.x); t1[5]=(short)f2bf(u3.y); t1[6]=(short)f2bf(u3.z); t1[7]=(short)f2bf(u3.w);
                int ke = hf * 32 + cp * 16;
                *(short8*)&Bs[base + (ke ^ sw)]       = t0;
                *(short8*)&Bs[base + ((ke + 8) ^ sw)] = t1;
            }
        }
        __syncthreads();
#pragma unroll
        for (int kt = 0; kt < 2; ++kt) {
            short8 a[4], b[4];
            int ke = kt * 32 + (lane >> 4) * 8;
#pragma unroll
            for (int mi = 0; mi < 4; ++mi) {
                int rr = wm * 64 + mi * 16 + (lane & 15);
                a[mi] = *(const short8*)&As[rr * 64 + (ke ^ ((rr & 7) << 3))];
            }
#pragma unroll
            for (int ni = 0; ni < 4; ++ni) {
                int rr = wn * 64 + ni * 16 + (lane & 15);
                b[ni] = *(const short8*)&Bs[rr * 64 + (ke ^ ((rr & 7) << 3))];
            }
#pragma unroll
            for (int mi = 0; mi < 4; ++mi)
#pragma unroll
                for (int ni = 0; ni < 4; ++ni)
                    acc[mi][ni] = __builtin_amdgcn_mfma_f32_16x16x32_bf16(a[mi], b[ni], acc[mi][ni], 0, 0, 0);
        }
    }
    // epilogue -> xpidx layout. t = mt, bblk = wm*4+mi, wv = nt*4+wn, n = ni,
    // g4 = lane>>4, c = lane&15, r packed as 4 consecutive u16 -> one uint2.
    int g4 = lane >> 4, c = lane & 15;
#pragma unroll
    for (int ni = 0; ni < 4; ++ni) {
        int col = nt * 256 + wn * 64 + ni * 16 + c;
        float bias = b_ih[col] + b_hh[col];
#pragma unroll
        for (int mi = 0; mi < 4; ++mi) {
            u32 lo = (u32)f2bf(acc[mi][ni][0] + bias) | ((u32)f2bf(acc[mi][ni][1] + bias) << 16);
            u32 hi = (u32)f2bf(acc[mi][ni][2] + bias) | ((u32)f2bf(acc[mi][ni][3] + bias) << 16);
            uint2 v; v.x = lo; v.y = hi;
            *reinterpret_cast<uint2*>(xp + xpidx(mt, wm * 4 + mi, nt * 4 + wn, ni, g4, c)) = v;
        }
    }
}

// ---------------------------------------------------------------------------
// Phase 2: recurrence. 8 blocks x 512 thr (8 waves), 1 block/CU.
// Wave wv owns H-cols [64wv, 64wv+64). W_hh fully resident:
//   kc 0..11 in registers (192 VGPR), kc 12..14 in LDS (96 KB), kc 15
//   streamed (L1-hit after first step). h double-buffered in 32 KB LDS.
// xp loaded per-step as coalesced dwordx2 in accumulator layout.
// ---------------------------------------------------------------------------
__global__ __launch_bounds__(512, 2) void rnn_rec_kernel(
    const u16* __restrict__ xp, const u16* __restrict__ Wp,
    u16* __restrict__ h_last) {
    __shared__ u16 W_lds[8 * 3 * 4 * 512];   // 96 KB
    __shared__ u16 h_s[2][16 * 512];         // 32 KB
    const int tid = threadIdx.x, lane = tid & 63, wv = tid >> 6;  // wv 0..7
    const int bb = blockIdx.x;
    const int g4 = lane >> 4, c = lane & 15;
    const int arow = lane & 15;
    const int asw = (arow & 7) << 3;

    // stage W kc=12..14 into LDS (each wave its own 12 KB slice)
#pragma unroll
    for (int f = 0; f < 12; ++f) {           // f = q*4 + n, q = kc-12
        int q = f >> 2, n = f & 3;
        short8 v = *(const short8*)(Wp + ((size_t)((wv * 16 + 12 + q) * 4 + n)) * 512 + lane * 8);
        *(short8*)&W_lds[((wv * 3 + q) * 4 + n) * 512 + lane * 8] = v;
    }
    // W kc=0..11 into registers (48 x short8 = 192 VGPR)
    short8 wr[12][4];
#pragma unroll
    for (int kc = 0; kc < 12; ++kc)
#pragma unroll
        for (int n = 0; n < 4; ++n)
            wr[kc][n] = *(const short8*)(Wp + ((size_t)((wv * 16 + kc) * 4 + n)) * 512 + lane * 8);

    // h(0) = 0
    *(short8*)&h_s[0][tid * 16]     = (short8)0;
    *(short8*)&h_s[0][tid * 16 + 8] = (short8)0;

    // prefetch xp(0)
    uint2 xn[4];
#pragma unroll
    for (int n = 0; n < 4; ++n)
        xn[n] = *(const uint2*)(xp + xpidx(0, bb, wv, n, g4, c));

    const u16* wp15 = Wp + ((size_t)(wv * 16 + 15) * 4) * 512 + lane * 8;

    __syncthreads();

    for (int t = 0; t < SEQ; ++t) {
        const int cur = t & 1, nxt = cur ^ 1;
        uint2 xc[4];
#pragma unroll
        for (int n = 0; n < 4; ++n) xc[n] = xn[n];
        if (t + 1 < SEQ) {
#pragma unroll
            for (int n = 0; n < 4; ++n)
                xn[n] = *(const uint2*)(xp + xpidx(t + 1, bb, wv, n, g4, c));
        }
        short8 w15[4];
#pragma unroll
        for (int n = 0; n < 4; ++n) w15[n] = *(const short8*)(wp15 + n * 512);

        f32x4 acc[4];
#pragma unroll
        for (int n = 0; n < 4; ++n) acc[n] = (f32x4){0.f, 0.f, 0.f, 0.f};

#pragma unroll
        for (int kc = 0; kc < 12; ++kc) {
            short8 a = *(const short8*)&h_s[cur][arow * 512 + ((kc * 32 + g4 * 8) ^ asw)];
#pragma unroll
            for (int n = 0; n < 4; ++n)
                acc[n] = __builtin_amdgcn_mfma_f32_16x16x32_bf16(a, wr[kc][n], acc[n], 0, 0, 0);
        }
#pragma unroll
        for (int q = 0; q < 3; ++q) {
            int kc = 12 + q;
            short8 a = *(const short8*)&h_s[cur][arow * 512 + ((kc * 32 + g4 * 8) ^ asw)];
#pragma unroll
            for (int n = 0; n < 4; ++n) {
                short8 b = *(const short8*)&W_lds[((wv * 3 + q) * 4 + n) * 512 + lane * 8];
                acc[n] = __builtin_amdgcn_mfma_f32_16x16x32_bf16(a, b, acc[n], 0, 0, 0);
            }
        }
        {
            short8 a = *(const short8*)&h_s[cur][arow * 512 + ((15 * 32 + g4 * 8) ^ asw)];
#pragma unroll
            for (int n = 0; n < 4; ++n)
                acc[n] = __builtin_amdgcn_mfma_f32_16x16x32_bf16(a, w15[n], acc[n], 0, 0, 0);
        }

        // epilogue: acc row r -> batch row 4*g4+r, col = wv*64 + n*16 + c
#pragma unroll
        for (int n = 0; n < 4; ++n) {
            float p0 = acc[n][0] + __uint_as_float(xc[n].x << 16);
            float p1 = acc[n][1] + __uint_as_float(xc[n].x & 0xffff0000u);
            float p2 = acc[n][2] + __uint_as_float(xc[n].y << 16);
            float p3 = acc[n][3] + __uint_as_float(xc[n].y & 0xffff0000u);
            int colL = wv * 64 + n * 16 + c;
#pragma unroll
            for (int r = 0; r < 4; ++r) {
                float p = (r == 0) ? p0 : (r == 1) ? p1 : (r == 2) ? p2 : p3;
                int row = 4 * g4 + r;
                h_s[nxt][row * 512 + (colL ^ ((row & 7) << 3))] = f2bf(tanh_fast(p));
            }
        }
        __syncthreads();
    }
    {   // final h is in h_s[0] (SEQ even). Un-swizzle and store 16 u16/thread.
        int i = tid * 16;
        int row = i >> 9, colb = i & 511;
        int sw = (row & 7) << 3;
        short8 v0 = *(const short8*)&h_s[0][row * 512 + (colb ^ sw)];
        short8 v1 = *(const short8*)&h_s[0][row * 512 + ((colb + 8) ^ sw)];
        *(short8*)(h_last + (size_t)(bb * 16 + row) * DH + colb)     = v0;
        *(short8*)(h_last + (size_t)(bb * 16 + row) * DH + colb + 8) = v1;
    }
}

// ---------------------------------------------------------------------------
// Phase 3: out[b][o] = h_last[b,:]·W_fc[o,:] + b_fc[o]   (fp32 VALU, tiny)
// ---------------------------------------------------------------------------
__global__ __launch_bounds__(256) void fc_kernel(
    const u16* __restrict__ h_last, const float* __restrict__ W_fc,
    const float* __restrict__ b_fc, float* __restrict__ out) {
    __shared__ float hsh[DH];
    int b = blockIdx.x, o = threadIdx.x;
    for (int i = threadIdx.x; i < DH; i += 256) hsh[i] = bf2f(h_last[(size_t)b * DH + i]);
    __syncthreads();
    const float* w = W_fc + (size_t)o * DH;
    float s = 0.f;
#pragma unroll 8
    for (int k = 0; k < DH; ++k) s += hsh[k] * w[k];
    out[(size_t)b * DOUT + o] = s + b_fc[o];
}

extern "C" void kernel_launch(void* const* d_in, const int* in_sizes, int n_in,
                              void* d_out, int out_size, void* d_ws, size_t ws_size,
                              hipStream_t stream) {
    const float* x    = (const float*)d_in[0];
    const float* W_ih = (const float*)d_in[1];
    const float* W_hh = (const float*)d_in[2];
    const float* b_ih = (const float*)d_in[3];
    const float* b_hh = (const float*)d_in[4];
    const float* W_fc = (const float*)d_in[5];
    const float* b_fc = (const float*)d_in[6];
    float* out = (float*)d_out;

    u16* xp     = (u16*)d_ws;                               // 2048*128*512 bf16 = 256 MB
    u16* Wp     = xp + (size_t)SEQ * BATCH * DH;            // 512 KB
    u16* h_last = Wp + (size_t)8 * 16 * 4 * 512;            // 128 KB

    hipLaunchKernelGGL(pack_whh_kernel, dim3(128), dim3(256), 0, stream, W_hh, Wp);
    hipLaunchKernelGGL(xproj_kernel, dim3(2048, 2), dim3(512), 0, stream, x, W_ih, b_ih, b_hh, xp);
    hipLaunchKernelGGL(rnn_rec_kernel, dim3(8), dim3(512), 0, stream, xp, Wp, h_last);
    hipLaunchKernelGGL(fc_kernel, dim3(128), dim3(256), 0, stream, h_last, W_fc, b_fc, out);
}